// Round 2
// baseline (483.189 us; speedup 1.0000x reference)
//
#include <hip/hip_runtime.h>
#include <hip/hip_bf16.h>

// VAE_RNN: B=4096, T=200, D=128, L=64, H=128, CIN=2L+D=256
// Persistent-block RNN: 256 blocks x 512 threads (8 waves), 16 batch rows per
// block for all 200 steps. Weights register-resident as bf16 MFMA fragments.
// Key trick: mfma(W_frag, act_frag, acc) computes (W^T @ h^T), so each lane's
// accumulator holds 4 CONSECUTIVE FEATURES of one batch row -> all activation
// stores/updates are vectorized (bf16x4/float4). 4 barriers per step.

#define NB 4096
#define NT 200
#define ND 128
#define NL 64
#define NH 128

typedef __bf16 bf16;
typedef __attribute__((ext_vector_type(8))) __bf16 bf16x8;
typedef __attribute__((ext_vector_type(4))) __bf16 bf16x4;
typedef __attribute__((ext_vector_type(4))) float f32x4;

__device__ __forceinline__ f32x4 mfma16(bf16x8 a, bf16x8 b, f32x4 c){
    return __builtin_amdgcn_mfma_f32_16x16x32_bf16(a, b, c, 0, 0, 0);
}

// inf-safe, branch-free: x->+inf: e=inf, rcp=0 -> 1; x->-inf: e=0 -> -1
__device__ __forceinline__ float fast_tanh(float x){
    float e = __expf(2.f * x);
    return 1.f - 2.f * __builtin_amdgcn_rcpf(e + 1.f);
}
__device__ __forceinline__ float fast_sigmoid(float x){
    float e = __expf(-x);
    return __builtin_amdgcn_rcpf(1.f + e);
}

__device__ __forceinline__ bf16x4 tanh4_bf16(f32x4 a, float4 b){
    bf16x4 o;
    o[0] = (bf16)fast_tanh(a[0] + b.x);
    o[1] = (bf16)fast_tanh(a[1] + b.y);
    o[2] = (bf16)fast_tanh(a[2] + b.z);
    o[3] = (bf16)fast_tanh(a[3] + b.w);
    return o;
}

__global__ __launch_bounds__(512, 2)
void vae_rnn(const float* __restrict__ data,
             const float* __restrict__ ug_w1, const float* __restrict__ ug_b1,
             const float* __restrict__ ug_w2, const float* __restrict__ ug_b2,
             const float* __restrict__ rg_w1, const float* __restrict__ rg_b1,
             const float* __restrict__ rg_w2, const float* __restrict__ rg_b2,
             const float* __restrict__ ns_w1, const float* __restrict__ ns_b1,
             const float* __restrict__ ns_w2, const float* __restrict__ ns_b2,
             float* __restrict__ out)
{
    // bf16 tiles, XOR-swizzled: byte = row*stride + ((col*2) ^ ((row&7)<<4))
    __shared__ __align__(16) char h_lds [16 * 512];   // 16 x 256 bf16: [y|s|x] / [y*r|s*r|x]
    __shared__ __align__(16) char t_lds [16 * 512];   // 16 x 256 bf16: tanh(l1) of [ug|rg]
    __shared__ __align__(16) char tn_lds[16 * 256];   // 16 x 128 bf16: tanh(l1) of ns
    __shared__ float u_lds [16][68];                  // u gate fp32 (stride 68: bank-shifted)
    __shared__ float ys_lds[16][132];                 // y (0..63), s (64..127) fp32, stride 132

    const int tid  = threadIdx.x;
    const int wave = tid >> 6;
    const int lane = tid & 63;
    const int lq   = lane >> 4;
    const int lc   = lane & 15;          // batch row within tile (output col after swap)
    const int sw   = (lc & 7) << 4;      // read swizzle for row lc
    const int row0 = blockIdx.x * 16;

    // ---------------- persistent weight fragments (bf16, registers) -------------
    // Used as A-operand of (W^T @ h^T): lane holds W[k = kt*32+lq*8+e][n = base+lc].
    bf16x8 wA[16]; float4 bA[2];
    #pragma unroll
    for (int j = 0; j < 2; ++j){
        int c = wave*32 + j*16 + lc;
        const float* W  = (c < 128) ? ug_w1 : rg_w1;
        int n = c & 127;
        int fb = (wave*32 + j*16 + lq*4) & 127;
        const float* bb = ((wave*32 + j*16) < 128) ? ug_b1 : rg_b1;
        bA[j] = make_float4(bb[fb], bb[fb+1], bb[fb+2], bb[fb+3]);
        #pragma unroll
        for (int kt = 0; kt < 8; ++kt){
            int k0 = kt*32 + lq*8;
            bf16x8 f;
            #pragma unroll
            for (int e = 0; e < 8; ++e) f[e] = (bf16)W[(k0 + e)*NH + n];
            wA[kt*2 + j] = f;
        }
    }
    bf16x8 wB[4]; float4 bB;
    {
        const float* W  = (wave < 4) ? ug_w2 : rg_w2;
        const float* bb = (wave < 4) ? ug_b2 : rg_b2;
        int n  = (wave & 3)*16 + lc;
        int fb = (wave & 3)*16 + lq*4;
        bB = make_float4(bb[fb], bb[fb+1], bb[fb+2], bb[fb+3]);
        #pragma unroll
        for (int kt = 0; kt < 4; ++kt){
            int k0 = kt*32 + lq*8;
            bf16x8 f;
            #pragma unroll
            for (int e = 0; e < 8; ++e) f[e] = (bf16)W[(k0 + e)*NL + n];
            wB[kt] = f;
        }
    }
    bf16x8 wC[8]; float4 bC;
    {
        int n  = wave*16 + lc;
        int fb = wave*16 + lq*4;
        bC = make_float4(ns_b1[fb], ns_b1[fb+1], ns_b1[fb+2], ns_b1[fb+3]);
        #pragma unroll
        for (int kt = 0; kt < 8; ++kt){
            int k0 = kt*32 + lq*8;
            bf16x8 f;
            #pragma unroll
            for (int e = 0; e < 8; ++e) f[e] = (bf16)ns_w1[(k0 + e)*NH + n];
            wC[kt] = f;
        }
    }
    bf16x8 wD[4]; float4 bD;
    {
        int n  = wave*16 + lc;
        int fb = wave*16 + lq*4;
        bD = make_float4(ns_b2[fb], ns_b2[fb+1], ns_b2[fb+2], ns_b2[fb+3]);
        #pragma unroll
        for (int kt = 0; kt < 4; ++kt){
            int k0 = kt*32 + lq*8;
            bf16x8 f;
            #pragma unroll
            for (int e = 0; e < 8; ++e) f[e] = (bf16)ns_w2[(k0 + e)*NH + n];
            wD[kt] = f;
        }
    }

    // init: ys = 0, h = [0 | 0 | x(0)]
    for (int i = tid; i < 16*132; i += 512) (&ys_lds[0][0])[i] = 0.f;
    const int xr = tid >> 5;             // 0..15
    const int xc = (tid & 31) << 2;      // 0..124
    const int swx = (xr & 7) << 4;
    const float* xbase = data + (size_t)(row0 + xr) * (NT * ND) + xc;
    {
        float4 x0 = *(const float4*)xbase;
        bf16x4 z = { (bf16)0.f, (bf16)0.f, (bf16)0.f, (bf16)0.f };
        bf16x4 xb = { (bf16)x0.x, (bf16)x0.y, (bf16)x0.z, (bf16)x0.w };
        *(bf16x4*)(h_lds + xr*512 + ((xc*2)       ^ swx)) = z;
        *(bf16x4*)(h_lds + xr*512 + (((128+xc)*2) ^ swx)) = xb;
    }
    __syncthreads();

    #pragma unroll 1
    for (int t = 0; t < NT; ++t){
        // prefetch x(t+1) — consumed at end of phase D
        float4 xnext = make_float4(0.f, 0.f, 0.f, 0.f);
        if (t + 1 < NT) xnext = *(const float4*)(xbase + (t + 1)*ND);

        // ---- Phase A: t = tanh(h @ [ug_w1|rg_w1] + b1), transposed-out ----
        {
            f32x4 acc[2][2] = {};
            #pragma unroll
            for (int kt = 0; kt < 8; ++kt){
                bf16x8 av = *(const bf16x8*)(h_lds + lc*512 + ((kt*64 + lq*16) ^ sw));
                acc[0][kt&1] = mfma16(wA[kt*2+0], av, acc[0][kt&1]);
                acc[1][kt&1] = mfma16(wA[kt*2+1], av, acc[1][kt&1]);
            }
            #pragma unroll
            for (int j = 0; j < 2; ++j){
                f32x4 a = acc[j][0] + acc[j][1];
                int f0 = wave*32 + j*16 + lq*4;
                *(bf16x4*)(t_lds + lc*512 + ((f0*2) ^ sw)) = tanh4_bf16(a, bA[j]);
            }
        }
        __syncthreads();

        // ---- Phase B: u|r = sigmoid(t_half @ w2 + b2); r-waves write hc ----
        {
            f32x4 acc = {};
            const int off = (wave < 4) ? 0 : 256;   // r-gate reads t cols 128..255
            #pragma unroll
            for (int kt = 0; kt < 4; ++kt){
                bf16x8 av = *(const bf16x8*)(t_lds + lc*512 + ((off + kt*64 + lq*16) ^ sw));
                acc = mfma16(wB[kt], av, acc);
            }
            int f0 = (wave & 3)*16 + lq*4;
            float g0 = fast_sigmoid(acc[0] + bB.x);
            float g1 = fast_sigmoid(acc[1] + bB.y);
            float g2 = fast_sigmoid(acc[2] + bB.z);
            float g3 = fast_sigmoid(acc[3] + bB.w);
            if (wave < 4){
                *(float4*)&u_lds[lc][f0] = make_float4(g0, g1, g2, g3);
            } else {
                float4 y4 = *(const float4*)&ys_lds[lc][f0];
                float4 s4 = *(const float4*)&ys_lds[lc][64 + f0];
                bf16x4 hy = { (bf16)(y4.x*g0), (bf16)(y4.y*g1), (bf16)(y4.z*g2), (bf16)(y4.w*g3) };
                bf16x4 hs = { (bf16)(s4.x*g0), (bf16)(s4.y*g1), (bf16)(s4.z*g2), (bf16)(s4.w*g3) };
                *(bf16x4*)(h_lds + lc*512 + ((f0*2)        ^ sw)) = hy;
                *(bf16x4*)(h_lds + lc*512 + (((64+f0)*2)   ^ sw)) = hs;
            }
        }
        __syncthreads();

        // ---- Phase C: tn = tanh(hc @ ns_w1 + ns_b1) ----
        {
            f32x4 acc[2] = {};
            #pragma unroll
            for (int kt = 0; kt < 8; ++kt){
                bf16x8 av = *(const bf16x8*)(h_lds + lc*512 + ((kt*64 + lq*16) ^ sw));
                acc[kt&1] = mfma16(wC[kt], av, acc[kt&1]);
            }
            f32x4 a = acc[0] + acc[1];
            int f0 = wave*16 + lq*4;
            *(bf16x4*)(tn_lds + lc*256 + ((f0*2) ^ sw)) = tanh4_bf16(a, bC);
        }
        __syncthreads();

        // ---- Phase D: ns = tn @ ns_w2 + b; EMA update; refresh h for t+1 ----
        {
            f32x4 acc = {};
            #pragma unroll
            for (int kt = 0; kt < 4; ++kt){
                bf16x8 av = *(const bf16x8*)(tn_lds + lc*256 + ((kt*64 + lq*16) ^ sw));
                acc = mfma16(wD[kt], av, acc);
            }
            int f0 = (wave & 3)*16 + lq*4;
            int sc = (wave >= 4) ? 64 : 0;           // std half lives at cols 64..127
            float v0 = acc[0] + bD.x, v1 = acc[1] + bD.y;
            float v2 = acc[2] + bD.z, v3 = acc[3] + bD.w;
            if (wave >= 4){ v0 = fabsf(v0); v1 = fabsf(v1); v2 = fabsf(v2); v3 = fabsf(v3); }
            float4 u4 = *(const float4*)&u_lds[lc][f0];
            float4 o4 = *(const float4*)&ys_lds[lc][sc + f0];
            float n0 = fmaf(u4.x, o4.x - v0, v0);
            float n1 = fmaf(u4.y, o4.y - v1, v1);
            float n2 = fmaf(u4.z, o4.z - v2, v2);
            float n3 = fmaf(u4.w, o4.w - v3, v3);
            *(float4*)&ys_lds[lc][sc + f0] = make_float4(n0, n1, n2, n3);
            bf16x4 hn = { (bf16)n0, (bf16)n1, (bf16)n2, (bf16)n3 };
            *(bf16x4*)(h_lds + lc*512 + (((sc + f0)*2) ^ sw)) = hn;
            // refresh x columns with x(t+1)
            bf16x4 xb = { (bf16)xnext.x, (bf16)xnext.y, (bf16)xnext.z, (bf16)xnext.w };
            *(bf16x4*)(h_lds + xr*512 + (((128+xc)*2) ^ swx)) = xb;
        }
        __syncthreads();
    }

    // output: yT (4096x64) then sT (4096x64), fp32
    {
        float4 v = *(const float4*)&ys_lds[xr][xc];
        size_t gr = (size_t)(row0 + xr);
        if (xc < 64) *(float4*)&out[gr*64 + xc] = v;
        else         *(float4*)&out[(size_t)NB*64 + gr*64 + (xc - 64)] = v;
    }
}

extern "C" void kernel_launch(void* const* d_in, const int* in_sizes, int n_in,
                              void* d_out, int out_size, void* d_ws, size_t ws_size,
                              hipStream_t stream) {
    const float* data  = (const float*)d_in[0];
    // d_in[1] = time_steps — unused by the reference computation
    const float* ug_w1 = (const float*)d_in[2];
    const float* ug_b1 = (const float*)d_in[3];
    const float* ug_w2 = (const float*)d_in[4];
    const float* ug_b2 = (const float*)d_in[5];
    const float* rg_w1 = (const float*)d_in[6];
    const float* rg_b1 = (const float*)d_in[7];
    const float* rg_w2 = (const float*)d_in[8];
    const float* rg_b2 = (const float*)d_in[9];
    const float* ns_w1 = (const float*)d_in[10];
    const float* ns_b1 = (const float*)d_in[11];
    const float* ns_w2 = (const float*)d_in[12];
    const float* ns_b2 = (const float*)d_in[13];

    hipLaunchKernelGGL(vae_rnn, dim3(NB/16), dim3(512), 0, stream,
                       data, ug_w1, ug_b1, ug_w2, ug_b2,
                       rg_w1, rg_b1, rg_w2, rg_b2,
                       ns_w1, ns_b1, ns_w2, ns_b2,
                       (float*)d_out);
}

// Round 3
// 400.966 us; speedup vs baseline: 1.2051x; 1.2051x over previous
//
#include <hip/hip_runtime.h>
#include <hip/hip_bf16.h>

// VAE_RNN: B=4096, T=200, D=128, L=64, H=128, CIN=2L+D=256
// Persistent-block RNN: 256 blocks x 512 threads (8 waves), 16 batch rows per
// block for all 200 steps. Weights register-resident as bf16 MFMA fragments.
// mfma(W_frag, act_frag, acc) computes (W^T @ h^T): lane holds 4 consecutive
// features of one batch row -> vectorized stores. 4 barriers/step.
// Barriers are RAW (lgkmcnt-only): the x(t+1) global prefetch stays in flight
// across all phase barriers (no vmcnt(0) drain), waited only at its use in D.

#define NB 4096
#define NT 200
#define ND 128
#define NL 64
#define NH 128

typedef __bf16 bf16;
typedef __attribute__((ext_vector_type(8))) __bf16 bf16x8;
typedef __attribute__((ext_vector_type(4))) __bf16 bf16x4;
typedef __attribute__((ext_vector_type(4))) float f32x4;

// lgkmcnt(0): my LDS writes are visible; s_barrier: all waves arrived.
// Deliberately does NOT drain vmcnt -> global prefetch spans barriers.
#define BAR() asm volatile("s_waitcnt lgkmcnt(0)\n\ts_barrier" ::: "memory")

__device__ __forceinline__ f32x4 mfma16(bf16x8 a, bf16x8 b, f32x4 c){
    return __builtin_amdgcn_mfma_f32_16x16x32_bf16(a, b, c, 0, 0, 0);
}

// inf-safe, branch-free
__device__ __forceinline__ float fast_tanh(float x){
    float e = __expf(2.f * x);
    return 1.f - 2.f * __builtin_amdgcn_rcpf(e + 1.f);
}
__device__ __forceinline__ float fast_sigmoid(float x){
    float e = __expf(-x);
    return __builtin_amdgcn_rcpf(1.f + e);
}

__device__ __forceinline__ bf16x4 tanh4_bf16(f32x4 a, float4 b){
    bf16x4 o;
    o[0] = (bf16)fast_tanh(a[0] + b.x);
    o[1] = (bf16)fast_tanh(a[1] + b.y);
    o[2] = (bf16)fast_tanh(a[2] + b.z);
    o[3] = (bf16)fast_tanh(a[3] + b.w);
    return o;
}

__global__ __launch_bounds__(512, 2)
void vae_rnn(const float* __restrict__ data,
             const float* __restrict__ ug_w1, const float* __restrict__ ug_b1,
             const float* __restrict__ ug_w2, const float* __restrict__ ug_b2,
             const float* __restrict__ rg_w1, const float* __restrict__ rg_b1,
             const float* __restrict__ rg_w2, const float* __restrict__ rg_b2,
             const float* __restrict__ ns_w1, const float* __restrict__ ns_b1,
             const float* __restrict__ ns_w2, const float* __restrict__ ns_b2,
             float* __restrict__ out)
{
    // bf16 tiles, XOR-swizzled: byte = row*stride + ((col*2) ^ ((row&7)<<4))
    __shared__ __align__(16) char h_lds [16 * 512];   // 16 x 256 bf16: [y|s|x] / [y*r|s*r|x]
    __shared__ __align__(16) char t_lds [16 * 512];   // 16 x 256 bf16: tanh(l1) of [ug|rg]
    __shared__ __align__(16) char tn_lds[16 * 256];   // 16 x 128 bf16: tanh(l1) of ns
    __shared__ float u_lds [16][68];                  // u gate fp32
    __shared__ float ys_lds[16][132];                 // y (0..63), s (64..127) fp32

    const int tid  = threadIdx.x;
    const int wave = tid >> 6;
    const int lane = tid & 63;
    const int lq   = lane >> 4;
    const int lc   = lane & 15;          // batch row within tile
    const int sw   = (lc & 7) << 4;      // read swizzle for row lc
    const int row0 = blockIdx.x * 16;

    // ---------------- persistent weight fragments (bf16, registers) -------------
    bf16x8 wA[16]; float4 bA[2];
    #pragma unroll
    for (int j = 0; j < 2; ++j){
        int c = wave*32 + j*16 + lc;
        const float* W  = (c < 128) ? ug_w1 : rg_w1;
        int n = c & 127;
        int fb = (wave*32 + j*16 + lq*4) & 127;
        const float* bb = ((wave*32 + j*16) < 128) ? ug_b1 : rg_b1;
        bA[j] = make_float4(bb[fb], bb[fb+1], bb[fb+2], bb[fb+3]);
        #pragma unroll
        for (int kt = 0; kt < 8; ++kt){
            int k0 = kt*32 + lq*8;
            bf16x8 f;
            #pragma unroll
            for (int e = 0; e < 8; ++e) f[e] = (bf16)W[(k0 + e)*NH + n];
            wA[kt*2 + j] = f;
        }
    }
    bf16x8 wB[4]; float4 bB;
    {
        const float* W  = (wave < 4) ? ug_w2 : rg_w2;
        const float* bb = (wave < 4) ? ug_b2 : rg_b2;
        int n  = (wave & 3)*16 + lc;
        int fb = (wave & 3)*16 + lq*4;
        bB = make_float4(bb[fb], bb[fb+1], bb[fb+2], bb[fb+3]);
        #pragma unroll
        for (int kt = 0; kt < 4; ++kt){
            int k0 = kt*32 + lq*8;
            bf16x8 f;
            #pragma unroll
            for (int e = 0; e < 8; ++e) f[e] = (bf16)W[(k0 + e)*NL + n];
            wB[kt] = f;
        }
    }
    bf16x8 wC[8]; float4 bC;
    {
        int n  = wave*16 + lc;
        int fb = wave*16 + lq*4;
        bC = make_float4(ns_b1[fb], ns_b1[fb+1], ns_b1[fb+2], ns_b1[fb+3]);
        #pragma unroll
        for (int kt = 0; kt < 8; ++kt){
            int k0 = kt*32 + lq*8;
            bf16x8 f;
            #pragma unroll
            for (int e = 0; e < 8; ++e) f[e] = (bf16)ns_w1[(k0 + e)*NH + n];
            wC[kt] = f;
        }
    }
    bf16x8 wD[4]; float4 bD;
    {
        int n  = wave*16 + lc;
        int fb = wave*16 + lq*4;
        bD = make_float4(ns_b2[fb], ns_b2[fb+1], ns_b2[fb+2], ns_b2[fb+3]);
        #pragma unroll
        for (int kt = 0; kt < 4; ++kt){
            int k0 = kt*32 + lq*8;
            bf16x8 f;
            #pragma unroll
            for (int e = 0; e < 8; ++e) f[e] = (bf16)ns_w2[(k0 + e)*NH + n];
            wD[kt] = f;
        }
    }

    // init: ys = 0, h = [0 | 0 | x(0)]
    for (int i = tid; i < 16*132; i += 512) (&ys_lds[0][0])[i] = 0.f;
    const int xr = tid >> 5;             // 0..15
    const int xc = (tid & 31) << 2;      // 0..124
    const int swx = (xr & 7) << 4;
    const float* xbase = data + (size_t)(row0 + xr) * (NT * ND) + xc;
    {
        float4 x0 = *(const float4*)xbase;
        bf16x4 z = { (bf16)0.f, (bf16)0.f, (bf16)0.f, (bf16)0.f };
        bf16x4 xb = { (bf16)x0.x, (bf16)x0.y, (bf16)x0.z, (bf16)x0.w };
        *(bf16x4*)(h_lds + xr*512 + ((xc*2)       ^ swx)) = z;
        *(bf16x4*)(h_lds + xr*512 + (((128+xc)*2) ^ swx)) = xb;
    }
    BAR();

    #pragma unroll 1
    for (int t = 0; t < NT; ++t){
        // prefetch x(t+1): pinned here by the asm barriers ("memory" clobber),
        // stays in flight through A/B/C (no vmcnt drain), consumed in D.
        int tn1 = (t + 1 < NT) ? (t + 1) : (NT - 1);
        float4 xnext = *(const float4*)(xbase + tn1*ND);

        bf16x8 xf[4];   // x-fragments cached A -> C

        // ---- Phase A: t = tanh(h @ [ug_w1|rg_w1] + b1), transposed-out ----
        {
            f32x4 acc[2][2] = {};
            #pragma unroll
            for (int kt = 0; kt < 8; ++kt){
                bf16x8 av = *(const bf16x8*)(h_lds + lc*512 + ((kt*64 + lq*16) ^ sw));
                if (kt >= 4) xf[kt-4] = av;
                acc[0][kt&1] = mfma16(wA[kt*2+0], av, acc[0][kt&1]);
                acc[1][kt&1] = mfma16(wA[kt*2+1], av, acc[1][kt&1]);
            }
            #pragma unroll
            for (int j = 0; j < 2; ++j){
                f32x4 a = acc[j][0] + acc[j][1];
                int f0 = wave*32 + j*16 + lq*4;
                *(bf16x4*)(t_lds + lc*512 + ((f0*2) ^ sw)) = tanh4_bf16(a, bA[j]);
            }
        }
        BAR();

        // ---- Phase B: u|r = sigmoid(t_half @ w2 + b2); r-waves write hc ----
        {
            // hoist state reads (stable since last D) ahead of the MFMAs
            float4 y4 = {}, s4 = {};
            int f0 = (wave & 3)*16 + lq*4;
            if (wave >= 4){
                y4 = *(const float4*)&ys_lds[lc][f0];
                s4 = *(const float4*)&ys_lds[lc][64 + f0];
            }
            f32x4 acc0 = {}, acc1 = {};
            const int off = (wave < 4) ? 0 : 256;
            #pragma unroll
            for (int kt = 0; kt < 4; ++kt){
                bf16x8 av = *(const bf16x8*)(t_lds + lc*512 + ((off + kt*64 + lq*16) ^ sw));
                if (kt & 1) acc1 = mfma16(wB[kt], av, acc1);
                else        acc0 = mfma16(wB[kt], av, acc0);
            }
            f32x4 acc = acc0 + acc1;
            float g0 = fast_sigmoid(acc[0] + bB.x);
            float g1 = fast_sigmoid(acc[1] + bB.y);
            float g2 = fast_sigmoid(acc[2] + bB.z);
            float g3 = fast_sigmoid(acc[3] + bB.w);
            if (wave < 4){
                *(float4*)&u_lds[lc][f0] = make_float4(g0, g1, g2, g3);
            } else {
                bf16x4 hy = { (bf16)(y4.x*g0), (bf16)(y4.y*g1), (bf16)(y4.z*g2), (bf16)(y4.w*g3) };
                bf16x4 hs = { (bf16)(s4.x*g0), (bf16)(s4.y*g1), (bf16)(s4.z*g2), (bf16)(s4.w*g3) };
                *(bf16x4*)(h_lds + lc*512 + ((f0*2)      ^ sw)) = hy;
                *(bf16x4*)(h_lds + lc*512 + (((64+f0)*2) ^ sw)) = hs;
            }
        }
        BAR();

        // ---- Phase C: tn = tanh(hc @ ns_w1 + b); also pre-read u/ys for D ----
        float4 u4, o4;
        {
            int fd = (wave & 3)*16 + lq*4;
            int sc = (wave >= 4) ? 64 : 0;
            u4 = *(const float4*)&u_lds[lc][fd];           // written in B, barrier passed
            o4 = *(const float4*)&ys_lds[lc][sc + fd];     // stable since last D

            f32x4 acc[2] = {};
            #pragma unroll
            for (int kt = 0; kt < 4; ++kt){
                bf16x8 av = *(const bf16x8*)(h_lds + lc*512 + ((kt*64 + lq*16) ^ sw));
                acc[kt&1] = mfma16(wC[kt], av, acc[kt&1]);
            }
            #pragma unroll
            for (int kt = 4; kt < 8; ++kt)
                acc[kt&1] = mfma16(wC[kt], xf[kt-4], acc[kt&1]);   // cached x-frags
            f32x4 a = acc[0] + acc[1];
            int f0 = wave*16 + lq*4;
            *(bf16x4*)(tn_lds + lc*256 + ((f0*2) ^ sw)) = tanh4_bf16(a, bC);
        }
        BAR();

        // ---- Phase D: ns = tn @ ns_w2 + b; EMA update; refresh h for t+1 ----
        {
            f32x4 acc0 = {}, acc1 = {};
            #pragma unroll
            for (int kt = 0; kt < 4; ++kt){
                bf16x8 av = *(const bf16x8*)(tn_lds + lc*256 + ((kt*64 + lq*16) ^ sw));
                if (kt & 1) acc1 = mfma16(wD[kt], av, acc1);
                else        acc0 = mfma16(wD[kt], av, acc0);
            }
            f32x4 acc = acc0 + acc1;
            int f0 = (wave & 3)*16 + lq*4;
            int sc = (wave >= 4) ? 64 : 0;
            float v0 = acc[0] + bD.x, v1 = acc[1] + bD.y;
            float v2 = acc[2] + bD.z, v3 = acc[3] + bD.w;
            if (wave >= 4){ v0 = fabsf(v0); v1 = fabsf(v1); v2 = fabsf(v2); v3 = fabsf(v3); }
            float n0 = fmaf(u4.x, o4.x - v0, v0);
            float n1 = fmaf(u4.y, o4.y - v1, v1);
            float n2 = fmaf(u4.z, o4.z - v2, v2);
            float n3 = fmaf(u4.w, o4.w - v3, v3);
            *(float4*)&ys_lds[lc][sc + f0] = make_float4(n0, n1, n2, n3);
            bf16x4 hn = { (bf16)n0, (bf16)n1, (bf16)n2, (bf16)n3 };
            *(bf16x4*)(h_lds + lc*512 + (((sc + f0)*2) ^ sw)) = hn;
            // refresh x columns with x(t+1) (vmcnt waited here, ~3 phases after issue)
            bf16x4 xb = { (bf16)xnext.x, (bf16)xnext.y, (bf16)xnext.z, (bf16)xnext.w };
            *(bf16x4*)(h_lds + xr*512 + (((128+xc)*2) ^ swx)) = xb;
        }
        BAR();
    }

    // output: yT (4096x64) then sT (4096x64), fp32
    {
        float4 v = *(const float4*)&ys_lds[xr][xc];
        size_t gr = (size_t)(row0 + xr);
        if (xc < 64) *(float4*)&out[gr*64 + xc] = v;
        else         *(float4*)&out[(size_t)NB*64 + gr*64 + (xc - 64)] = v;
    }
}

extern "C" void kernel_launch(void* const* d_in, const int* in_sizes, int n_in,
                              void* d_out, int out_size, void* d_ws, size_t ws_size,
                              hipStream_t stream) {
    const float* data  = (const float*)d_in[0];
    // d_in[1] = time_steps — unused by the reference computation
    const float* ug_w1 = (const float*)d_in[2];
    const float* ug_b1 = (const float*)d_in[3];
    const float* ug_w2 = (const float*)d_in[4];
    const float* ug_b2 = (const float*)d_in[5];
    const float* rg_w1 = (const float*)d_in[6];
    const float* rg_b1 = (const float*)d_in[7];
    const float* rg_w2 = (const float*)d_in[8];
    const float* rg_b2 = (const float*)d_in[9];
    const float* ns_w1 = (const float*)d_in[10];
    const float* ns_b1 = (const float*)d_in[11];
    const float* ns_w2 = (const float*)d_in[12];
    const float* ns_b2 = (const float*)d_in[13];

    hipLaunchKernelGGL(vae_rnn, dim3(NB/16), dim3(512), 0, stream,
                       data, ug_w1, ug_b1, ug_w2, ug_b2,
                       rg_w1, rg_b1, rg_w2, rg_b2,
                       ns_w1, ns_b1, ns_w2, ns_b2,
                       (float*)d_out);
}